// Round 1
// baseline (2787.329 us; speedup 1.0000x reference)
//
#include <hip/hip_runtime.h>
#include <hip/hip_bf16.h>

// Sizes (fixed by the problem)
#define BSZ  4096
#define TS   31
#define DIN  124
#define HH   256
#define FEA  64
#define VV   20
#define NCC  100

typedef __attribute__((ext_vector_type(8))) short bf16x8;   // 8 bf16 = 4 VGPR
typedef __attribute__((ext_vector_type(4))) float f32x4;

// workspace byte offsets
#define OFF_WHH0   0u           // 64 tiles * 8 kk * 1024B = 512 KB (bf16 frag-packed)
#define OFF_WIH1   524288u
#define OFF_WHH1   1048576u
#define OFF_WHEAD  1572864u     // 8 tiles -> 64 KB
#define OFF_BG0    1638400u     // 1024 f32
#define OFF_BG1    1642496u     // 1024 f32
#define OFF_BHEAD  1646592u     // 128 f32

__device__ __forceinline__ unsigned short f2bf(float f) {
    unsigned int u = __float_as_uint(f);
    unsigned int r = (u + 0x7FFFu + ((u >> 16) & 1u)) >> 16;
    return (unsigned short)r;
}
__device__ __forceinline__ float sigmoidf_(float x) {
    return 1.f / (1.f + __expf(-x));
}
__device__ __forceinline__ float tanhf_(float x) {
    float ax = fabsf(x);
    float e = __expf(-2.f * ax);          // (0,1], no overflow
    float t = (1.f - e) / (1.f + e);
    return copysignf(t, x);
}

// ---------------------------------------------------------------------------
// Prep: pack Whh0/Wih1/Whh1/Whead into MFMA-fragment-contiguous bf16 blocks.
// Fragment block fb = tile*8+kk is 64 lanes * 16B contiguous; lane l holds
// W[16*tile + (l&15)][kk*32 + (l>>4)*8 + j], j=0..7  (B-operand layout of
// v_mfma_f32_16x16x32_bf16). Also fuse biases.
// ---------------------------------------------------------------------------
__global__ __launch_bounds__(256) void prep_kernel(
    const float* __restrict__ Whh0, const float* __restrict__ Wih1,
    const float* __restrict__ Whh1, const float* __restrict__ Wout,
    const float* __restrict__ Wcv,
    const float* __restrict__ bih0, const float* __restrict__ bhh0,
    const float* __restrict__ bih1, const float* __restrict__ bhh1,
    const float* __restrict__ bout, const float* __restrict__ bcv,
    char* __restrict__ ws)
{
    int u = blockIdx.x * 256 + threadIdx.x;
    if (u < 102400) {                       // 200 tiles * 8 kk * 64 lanes
        int tg  = u >> 9;                   // global tile 0..199
        int rem = u & 511;
        int kk  = rem >> 6;
        int l   = rem & 63;
        const float* src = nullptr;
        int tile;
        unsigned short* dst;
        if (tg < 64)       { src = Whh0; tile = tg;        dst = (unsigned short*)(ws + OFF_WHH0); }
        else if (tg < 128) { src = Wih1; tile = tg - 64;   dst = (unsigned short*)(ws + OFF_WIH1); }
        else if (tg < 192) { src = Whh1; tile = tg - 128;  dst = (unsigned short*)(ws + OFF_WHH1); }
        else               {             tile = tg - 192;  dst = (unsigned short*)(ws + OFF_WHEAD); }
        int row = tile * 16 + (l & 15);
        int k0  = kk * 32 + (l >> 4) * 8;
        unsigned short tmp[8];
        #pragma unroll
        for (int j = 0; j < 8; j++) {
            float v;
            if (src)            v = src[row * HH + k0 + j];
            else if (row < 20)  v = Wout[row * HH + k0 + j];
            else if (row < 120) v = Wcv[(row - 20) * HH + k0 + j];
            else                v = 0.f;
            tmp[j] = f2bf(v);
        }
        ((int4*)dst)[(tile * 8 + kk) * 64 + l] = *(const int4*)tmp;
    } else if (u < 102400 + 1024) {
        int g = u - 102400;
        ((float*)(ws + OFF_BG0))[g] = bih0[g] + bhh0[g];
    } else if (u < 102400 + 2048) {
        int g = u - 102400 - 1024;
        ((float*)(ws + OFF_BG1))[g] = bih1[g] + bhh1[g];
    } else if (u < 102400 + 2048 + 128) {
        int v = u - 102400 - 2048;
        float b = (v < 20) ? bout[v] : (v < 120 ? bcv[v - 20] : 0.f);
        ((float*)(ws + OFF_BHEAD))[v] = b;
    }
}

// ---------------------------------------------------------------------------
// Main: 256 blocks (1/CU) * 1024 threads (16 waves). Block owns 16 batch rows,
// runs all 31 steps locally. Wave w owns hidden slice [16w,16w+16): gate tiles
// {w, 16+w, 32+w, 48+w} (i,f,g,o). c-state + xacc in registers, h0/h1 in LDS.
// ---------------------------------------------------------------------------
__global__ __launch_bounds__(1024) void lstm_main(
    const float* __restrict__ x,        // [4096,64]
    const int*   __restrict__ choices,  // [4096,31]
    const int*   __restrict__ masks,    // [4096,31,20]
    const int*   __restrict__ c_idx,    // [4096,31]
    const int*   __restrict__ c_choice, // [4096,31]
    const float* __restrict__ Wih0,     // [1024,124] f32
    const float* __restrict__ Wxc,      // [256,64]
    const float* __restrict__ bxc,      // [256]
    const char*  __restrict__ ws,
    float* __restrict__ out)            // [4096]
{
    const int tid  = threadIdx.x;
    const int w    = tid >> 6;          // wave 0..15
    const int lane = tid & 63;
    const int l15  = lane & 15;
    const int l4   = lane >> 4;         // 0..3
    const int b0   = blockIdx.x * 16;

    __shared__ unsigned short hs0[16][264];   // bf16, padded stride
    __shared__ unsigned short hs1[16][264];
    __shared__ float headbuf[16][132];
    __shared__ float xrow[16][64];
    __shared__ float lp_s[16];
    __shared__ int   ch_s[16];

    const bf16x8* pWhh0  = (const bf16x8*)(ws + OFF_WHH0);
    const bf16x8* pWih1  = (const bf16x8*)(ws + OFF_WIH1);
    const bf16x8* pWhh1  = (const bf16x8*)(ws + OFF_WHH1);
    const bf16x8* pWhead = (const bf16x8*)(ws + OFF_WHEAD);
    const float* bg0   = (const float*)(ws + OFF_BG0);
    const float* bg1   = (const float*)(ws + OFF_BG1);
    const float* bhead = (const float*)(ws + OFF_BHEAD);

    for (int i = tid; i < 16 * 264; i += 1024) {
        ((unsigned short*)hs0)[i] = 0;
        ((unsigned short*)hs1)[i] = 0;
    }
    xrow[tid >> 6][tid & 63] = x[(b0 + (tid >> 6)) * FEA + (tid & 63)];
    if (tid < 16) lp_s[tid] = 0.f;
    __syncthreads();

    // c0 = x @ Wxc.T + bxc  (both layers start from it)
    const int hid = 16 * w + l15;
    float c0r[4], c1r[4];
    {
        float acc[4] = {0.f, 0.f, 0.f, 0.f};
        const float4* wxc4 = (const float4*)(Wxc + hid * FEA);
        #pragma unroll
        for (int k4 = 0; k4 < 16; k4++) {
            float4 wv = wxc4[k4];
            #pragma unroll
            for (int r = 0; r < 4; r++) {
                const float4 xv = *(const float4*)&xrow[l4 * 4 + r][k4 * 4];
                acc[r] += wv.x * xv.x + wv.y * xv.y + wv.z * xv.z + wv.w * xv.w;
            }
        }
        float bb = bxc[hid];
        #pragma unroll
        for (int r = 0; r < 4; r++) { c0r[r] = acc[r] + bb; c1r[r] = acc[r] + bb; }
    }

    float xacc[4][4];
    #pragma unroll
    for (int g = 0; g < 4; g++)
        #pragma unroll
        for (int r = 0; r < 4; r++) xacc[g][r] = 0.f;

    for (int t = 0; t < TS; t++) {
        if (tid < 16) ch_s[tid] = choices[(b0 + tid) * TS + t];

        // ---------------- layer 0 ----------------
        bf16x8 a[8];
        #pragma unroll
        for (int kk = 0; kk < 8; kk++)
            a[kk] = *(const bf16x8*)&hs0[l15][kk * 32 + l4 * 8];

        f32x4 acc0[4];
        #pragma unroll
        for (int g = 0; g < 4; g++) {
            int tile = g * 16 + w;
            float bb = bg0[tile * 16 + l15];
            f32x4 c; c[0] = bb + xacc[g][0]; c[1] = bb + xacc[g][1];
                     c[2] = bb + xacc[g][2]; c[3] = bb + xacc[g][3];
            const bf16x8* pb = pWhh0 + tile * 512 + lane;
            bf16x8 bfr[8];
            #pragma unroll
            for (int kk = 0; kk < 8; kk++) bfr[kk] = pb[kk * 64];
            #pragma unroll
            for (int kk = 0; kk < 8; kk++)
                c = __builtin_amdgcn_mfma_f32_16x16x32_bf16(a[kk], bfr[kk], c, 0, 0, 0);
            acc0[g] = c;
        }
        __syncthreads();   // all A-reads of hs0 done before overwrite
        #pragma unroll
        for (int r = 0; r < 4; r++) {
            float iv = sigmoidf_(acc0[0][r]);
            float fv = sigmoidf_(acc0[1][r]);
            float gv = tanhf_(acc0[2][r]);
            float ov = sigmoidf_(acc0[3][r]);
            float cn = fv * c0r[r] + iv * gv;
            c0r[r] = cn;
            hs0[l4 * 4 + r][hid] = f2bf(ov * tanhf_(cn));
        }
        __syncthreads();   // hs0 new visible

        // ---------------- layer 1 ----------------
        bf16x8 a0[8], a1[8];
        #pragma unroll
        for (int kk = 0; kk < 8; kk++) {
            a0[kk] = *(const bf16x8*)&hs0[l15][kk * 32 + l4 * 8];
            a1[kk] = *(const bf16x8*)&hs1[l15][kk * 32 + l4 * 8];
        }
        f32x4 acc1[4];
        #pragma unroll
        for (int g = 0; g < 4; g++) {
            int tile = g * 16 + w;
            float bb = bg1[tile * 16 + l15];
            f32x4 c; c[0] = bb; c[1] = bb; c[2] = bb; c[3] = bb;
            const bf16x8* pb  = pWih1 + tile * 512 + lane;
            const bf16x8* pb2 = pWhh1 + tile * 512 + lane;
            bf16x8 bfr[8], bfr2[8];
            #pragma unroll
            for (int kk = 0; kk < 8; kk++) { bfr[kk] = pb[kk * 64]; bfr2[kk] = pb2[kk * 64]; }
            #pragma unroll
            for (int kk = 0; kk < 8; kk++)
                c = __builtin_amdgcn_mfma_f32_16x16x32_bf16(a0[kk], bfr[kk], c, 0, 0, 0);
            #pragma unroll
            for (int kk = 0; kk < 8; kk++)
                c = __builtin_amdgcn_mfma_f32_16x16x32_bf16(a1[kk], bfr2[kk], c, 0, 0, 0);
            acc1[g] = c;
        }
        __syncthreads();   // hs1 A-reads done
        #pragma unroll
        for (int r = 0; r < 4; r++) {
            float iv = sigmoidf_(acc1[0][r]);
            float fv = sigmoidf_(acc1[1][r]);
            float gv = tanhf_(acc1[2][r]);
            float ov = sigmoidf_(acc1[3][r]);
            float cn = fv * c1r[r] + iv * gv;
            c1r[r] = cn;
            hs1[l4 * 4 + r][hid] = f2bf(ov * tanhf_(cn));
        }
        __syncthreads();

        // ---------------- heads: [16,256] x [256,128] ----------------
        if (w < 8) {
            bf16x8 ah[8];
            #pragma unroll
            for (int kk = 0; kk < 8; kk++)
                ah[kk] = *(const bf16x8*)&hs1[l15][kk * 32 + l4 * 8];
            float bb = bhead[w * 16 + l15];
            f32x4 c; c[0] = bb; c[1] = bb; c[2] = bb; c[3] = bb;
            const bf16x8* pb = pWhead + w * 512 + lane;
            bf16x8 bfr[8];
            #pragma unroll
            for (int kk = 0; kk < 8; kk++) bfr[kk] = pb[kk * 64];
            #pragma unroll
            for (int kk = 0; kk < 8; kk++)
                c = __builtin_amdgcn_mfma_f32_16x16x32_bf16(ah[kk], bfr[kk], c, 0, 0, 0);
            #pragma unroll
            for (int r = 0; r < 4; r++)
                headbuf[l4 * 4 + r][w * 16 + l15] = c[r];
        }
        __syncthreads();

        // ---------------- softmaxes + lp (wave w -> row w) ----------------
        {
            const int row = w;
            const int b = b0 + row;
            const int ch = ch_s[row];
            float v1;
            if (lane < VV) {
                int mk = masks[(b * TS + t) * VV + lane];
                v1 = mk ? headbuf[row][lane] : -1e9f;
            } else v1 = -__builtin_inff();
            float m = v1;
            #pragma unroll
            for (int off = 32; off; off >>= 1) m = fmaxf(m, __shfl_xor(m, off));
            float e = (lane < VV) ? __expf(v1 - m) : 0.f;
            #pragma unroll
            for (int off = 32; off; off >>= 1) e += __shfl_xor(e, off);
            float lse = m + __logf(e);
            float lv_ch = __shfl(v1, ch);
            float lpadd = lv_ch - lse;

            float a1v = headbuf[row][20 + lane];
            float a2v = (lane < 36) ? headbuf[row][84 + lane] : -__builtin_inff();
            float mc = fmaxf(a1v, a2v);
            #pragma unroll
            for (int off = 32; off; off >>= 1) mc = fmaxf(mc, __shfl_xor(mc, off));
            float ec = __expf(a1v - mc) + ((lane < 36) ? __expf(a2v - mc) : 0.f);
            #pragma unroll
            for (int off = 32; off; off >>= 1) ec += __shfl_xor(ec, off);
            float lsec = mc + __logf(ec);
            if (lane == 0) {
                int ci = c_idx[b * TS + t];
                float add2 = 0.f;
                if (ci) {
                    int cc = c_choice[b * TS + t];
                    add2 = headbuf[row][20 + cc] - lsec;
                }
                lp_s[row] += lpadd + add2;
            }
        }

        // ---------------- xacc += chosen-token bit columns of Wih0 ----------
        if (t < TS - 1) {
            #pragma unroll
            for (int g = 0; g < 4; g++) {
                int gate = g * 256 + 16 * w + l15;
                const float4 wv = *(const float4*)&Wih0[gate * DIN + 4 * t];
                #pragma unroll
                for (int r = 0; r < 4; r++) {
                    int ch = ch_s[l4 * 4 + r];
                    xacc[g][r] += (((ch >> 3) & 1) ? wv.x : 0.f)
                                + (((ch >> 2) & 1) ? wv.y : 0.f)
                                + (((ch >> 1) & 1) ? wv.z : 0.f)
                                + (((ch     ) & 1) ? wv.w : 0.f);
                }
            }
        }
        __syncthreads();   // protects ch_s / headbuf rewrite next step
    }

    if (tid < 16) out[b0 + tid] = lp_s[tid];
}

extern "C" void kernel_launch(void* const* d_in, const int* in_sizes, int n_in,
                              void* d_out, int out_size, void* d_ws, size_t ws_size,
                              hipStream_t stream) {
    const float* x        = (const float*)d_in[0];
    const int*   choices  = (const int*)d_in[1];
    const int*   masks    = (const int*)d_in[2];
    const int*   c_idx    = (const int*)d_in[3];
    const int*   c_choice = (const int*)d_in[4];
    const float* Wih0 = (const float*)d_in[5];
    const float* Whh0 = (const float*)d_in[6];
    const float* bih0 = (const float*)d_in[7];
    const float* bhh0 = (const float*)d_in[8];
    const float* Wih1 = (const float*)d_in[9];
    const float* Whh1 = (const float*)d_in[10];
    const float* bih1 = (const float*)d_in[11];
    const float* bhh1 = (const float*)d_in[12];
    const float* Wout = (const float*)d_in[13];
    const float* bout = (const float*)d_in[14];
    const float* Wxc  = (const float*)d_in[15];
    const float* bxc  = (const float*)d_in[16];
    const float* Wcv  = (const float*)d_in[17];
    const float* bcv  = (const float*)d_in[18];
    char* ws = (char*)d_ws;

    hipLaunchKernelGGL(prep_kernel, dim3(409), dim3(256), 0, stream,
                       Whh0, Wih1, Whh1, Wout, Wcv,
                       bih0, bhh0, bih1, bhh1, bout, bcv, ws);
    hipLaunchKernelGGL(lstm_main, dim3(256), dim3(1024), 0, stream,
                       x, choices, masks, c_idx, c_choice,
                       Wih0, Wxc, bxc, ws, (float*)d_out);
}